// Round 8
// baseline (458.517 us; speedup 1.0000x reference)
//
#include <hip/hip_runtime.h>

#define NBATCH 8
#define TW 64          // tile width  (output)
#define TH 32          // tile height (output)
#define SROWS 42       // staged rows: image rows -5..36  (TH + 10)
#define SQUADS 20      // staged data quads/row: image cols -8..71 (80 floats)
#define STRDQ 80       // LDS row stride in floats (20 quads, rotation mod 20)
#define NPAIRS 20      // region row-pairs (region rows -4..35)
#define NSTRIP 180     // 20 row-pairs x 9 col-octs
#define NTHR 192
// LDS: ONE 42-row buffer @ 80 floats = 13440 B. In-place ping-pong: per step,
// all window reads complete (mid-barrier) before any in-place write. This
// halves LDS vs the 2-buffer scheme -> 10 blocks/CU (30 waves, wave-capped),
// +67% resident waves to hide the barrier/latency stalls the R3-R7 counters
// showed (all pipes <=45% busy at 18 waves). Cost: 9 barriers vs 5.

// ---------------------------------------------------------------------------
// Swizzled LDS layout: logical quad q (0..19) of row R lives at physical quad
// (q + 3*(R>>1)) mod 20. Bank 4-group of an access = lane-varying (2j + 3rp)
// mod 8 balanced by the posmap strip assignment; the mod-20 wrap adds an
// approximate +4 perturbation (accepted, measured ~0.8e7 counter at R7).
// ---------------------------------------------------------------------------
__device__ __forceinline__ int lofs(int R, int q) {   // float offset of (row,quad)
    int rot = (3 * (R >> 1)) % 20;
    int p = q + rot;
    if (p >= 20) p -= 20;
    return R * STRDQ + (p << 2);
}

// accumulate one stencil row: window floats [L, m.x..m.w, R], weights ka,kb,kc
__device__ __forceinline__ void acc_row(float4& v, float L, float4 m, float R,
                                        float ka, float kb, float kc) {
    v.x += ka * L   + kb * m.x + kc * m.y;
    v.y += ka * m.x + kb * m.y + kc * m.z;
    v.z += ka * m.y + kb * m.z + kc * m.w;
    v.w += ka * m.z + kb * m.w + kc * R;
}

// clamp to [-1,1] then apply precomputed mask; all LDS inputs are finite by
// construction (buffer fully staged from finite input; rim cells keep staged
// halo data forever), so fmed3 NaN semantics never engage and out-of-image
// padding cells stay exactly 0.
__device__ __forceinline__ void clamp_mask(float4& v, float4 pm) {
    v.x = __builtin_amdgcn_fmed3f(v.x, -1.0f, 1.0f) * pm.x;
    v.y = __builtin_amdgcn_fmed3f(v.y, -1.0f, 1.0f) * pm.y;
    v.z = __builtin_amdgcn_fmed3f(v.z, -1.0f, 1.0f) * pm.z;
    v.w = __builtin_amdgcn_fmed3f(v.w, -1.0f, 1.0f) * pm.w;
}

// ---------------------------------------------------------------------------
// 5 fused conv3x3+bias+BU+clamp iterations; all 3 pyramid levels, one dispatch.
// One 64x32 output tile per 192-thread block. Single LDS buffer, in-place:
// per step {barrier; read window to regs; barrier; compute+write}. Thread t
// (<180) owns one 8x2-px strip. Window regs kept small: 4 middle float4s
// (rows 0,3) + 8 edge scalars (only .w/.x of edge quads are used) + 4 center
// float4s from this thread's own previous write (register mirror, steps 2-5).
// Step 5 stores result registers directly to global (interior-masked) with
// no mid-barrier or LDS write. Writes cover rows 1..40, quads 1..18; rim
// cells keep their staged halo values -- reads of them only feed eroded-ring
// cells, identical validity argument to the 2-buffer scheme. Out-of-image
// cells re-masked to 0 every iter (true zero-pad semantics at image edges).
// ---------------------------------------------------------------------------
__global__ __launch_bounds__(NTHR, 8) void conv5_all(
    const float* __restrict__ srcU, const float* __restrict__ buU,
    const float* __restrict__ wtU, const float* __restrict__ bsU,
    const float* __restrict__ srcX, const float* __restrict__ buX,
    const float* __restrict__ wtX, const float* __restrict__ bsX,
    const float* __restrict__ srcD, const float* __restrict__ buD,
    const float* __restrict__ wtD, const float* __restrict__ bsD,
    float* __restrict__ dstU, float* __restrict__ dstX, float* __restrict__ dstD)
{
    __shared__ __align__(16) float buf[SROWS * STRDQ];

    const int tid = threadIdx.x;
    const int blk = blockIdx.x;

    const float* src; const float* BU; const float* wt; const float* bs;
    float* dst; int HW; int tx, ty, b;
    if (blk < 4096) {                 // up: 8 x (32 ty x 16 tx)
        src = srcU; BU = buU; wt = wtU; bs = bsU; dst = dstU; HW = 1024;
        b = blk >> 9; int rem = blk & 511; ty = rem >> 4; tx = rem & 15;
    } else if (blk < 5120) {          // x: 8 x (16 ty x 8 tx)
        int t = blk - 4096;
        src = srcX; BU = buX; wt = wtX; bs = bsX; dst = dstX; HW = 512;
        b = t >> 7; int rem = t & 127; ty = rem >> 3; tx = rem & 7;
    } else {                          // down: 8 x (8 ty x 4 tx)
        int t = blk - 5120;
        src = srcD; BU = buD; wt = wtD; bs = bsD; dst = dstD; HW = 256;
        b = t >> 5; int rem = t & 31; ty = rem >> 2; tx = rem & 3;
    }
    const int bh0 = ty * TH, bw0 = tx * TW;
    const long base = (long)b * HW * HW;

    // ---- stage: image rows -5..36, cols -8..71 -> buf (img col c -> data quad (c+8)/4)
    for (int s = tid; s < SROWS * SQUADS; s += NTHR) {
        int r = s / SQUADS, cq = s - r * SQUADS;
        int gh = bh0 + r - 5;
        int gw = bw0 + (cq << 2) - 8;
        float4 v = {0.0f, 0.0f, 0.0f, 0.0f};
        if ((unsigned)gh < (unsigned)HW) {
            const float* gp = src + base + (long)gh * HW + gw;
            if (gw >= 0 && gw + 3 < HW) {
                v = *(const float4*)gp;
            } else {
                if ((unsigned)(gw + 0) < (unsigned)HW) v.x = gp[0];
                if ((unsigned)(gw + 1) < (unsigned)HW) v.y = gp[1];
                if ((unsigned)(gw + 2) < (unsigned)HW) v.z = gp[2];
                if ((unsigned)(gw + 3) < (unsigned)HW) v.w = gp[3];
            }
        }
        *(float4*)&buf[lofs(r, cq)] = v;
    }

    const float k00 = wt[0], k01 = wt[1], k02 = wt[2];
    const float k10 = wt[3], k11 = wt[4], k12 = wt[5];
    const float k20 = wt[6], k21 = wt[7], k22 = wt[8];
    const float bias = bs[0];

    // ---- strip assignment: thread t -> (t>>3)-th strip of bank-group
    // posmap[t&7] (balances the un-wrapped (2j+3rp) mod 8 component).
    // Groups {0,1,3,6} have 23 strips, {2,4,5,7} have 22. Within row-pair rp,
    // strips of group g exist iff rp parity == g parity, at j = j0 + 4*m
    // (j0 = ((g-3rp)&7)>>1; m = 0..2 if j0==0 else 0..1).
    const bool act = (tid < NSTRIP);
    int rp = 0, j = 0;
    {
        int g = (0x75426310u >> ((tid & 7) << 2)) & 0xF;  // posmap {0,1,3,6,2,4,5,7}
        int need = tid >> 3;
        for (int r_ = (g & 1); r_ < NPAIRS; r_ += 2) {
            int j0 = ((g - 3 * r_) & 7) >> 1;             // 0..3
            int c = (j0 == 0) ? 3 : 2;
            if (need < c) { rp = r_; j = j0 + 4 * need; break; }
            need -= c;
        }
    }

    // precomputed swizzled LDS offsets (constant across all 5 steps):
    // middle quads (b128) at logical quads 2j+1, 2j+2; edge floats (b32)
    // L = quad 2j elem 3, R = quad 2j+3 elem 0.
    int rdm[4][2];
    int e0o[4], e3o[4];
    #pragma unroll
    for (int r = 0; r < 4; ++r) {
        rdm[r][0] = lofs(2 * rp + r, 2 * j + 1);
        rdm[r][1] = lofs(2 * rp + r, 2 * j + 2);
        e0o[r]    = lofs(2 * rp + r, 2 * j) + 3;
        e3o[r]    = lofs(2 * rp + r, 2 * j + 3);
    }
    // write offsets == rdm[1..2][0..1] (rows 2rp+1..2, quads 2j+1..2)

    // ---- premultiplied masks pm = hf(row-in-image) * wf(col-in-image)
    float4 pm0[2], pm1[2];
    float hf[2];
    #pragma unroll
    for (int i = 0; i < 2; ++i) {
        int gh = bh0 + 2 * rp - 4 + i;
        hf[i] = (act && (unsigned)gh < (unsigned)HW) ? 1.0f : 0.0f;
        float* p0 = (float*)&pm0[i]; float* p1 = (float*)&pm1[i];
        #pragma unroll
        for (int k = 0; k < 4; ++k) {
            p0[k] = hf[i] * (((unsigned)(bw0 + 8 * j - 4 + k) < (unsigned)HW) ? 1.0f : 0.0f);
            p1[k] = hf[i] * (((unsigned)(bw0 + 8 * j + k)     < (unsigned)HW) ? 1.0f : 0.0f);
        }
    }
    float4 bu0[2], bu1[2];            // (BU + bias), pre-masked 0 outside image
    #pragma unroll
    for (int i = 0; i < 2; ++i) {
        int gh = bh0 + 2 * rp - 4 + i;
        bool hok = (hf[i] != 0.0f);
        int gw0 = bw0 + 8 * j - 4;    // 4-aligned
        const float* bp = BU + base + (long)gh * HW + gw0;
        if (hok && gw0 >= 0 && gw0 + 7 < HW) {
            // interior fast path: two aligned float4 loads
            float4 a = *(const float4*)bp;
            float4 c = *(const float4*)(bp + 4);
            bu0[i] = {a.x + bias, a.y + bias, a.z + bias, a.w + bias};
            bu1[i] = {c.x + bias, c.y + bias, c.z + bias, c.w + bias};
        } else {
            float* b0 = (float*)&bu0[i]; float* b1 = (float*)&bu1[i];
            #pragma unroll
            for (int k = 0; k < 4; ++k) {
                int w0 = gw0 + k;
                int w1 = gw0 + 4 + k;
                b0[k] = (hok && (unsigned)w0 < (unsigned)HW) ? (bp[k] + bias)     : 0.0f;
                b1[k] = (hok && (unsigned)w1 < (unsigned)HW) ? (bp[k + 4] + bias) : 0.0f;
            }
        }
    }

    // center quads this thread wrote last step (registers mirror LDS exactly)
    float4 prev0[2], prev1[2];

    // ---- one in-place conv step:
    //   barrier (prev writes / staging visible) -> read window to regs ->
    //   barrier (all reads done) -> compute -> write in place (or store
    //   directly to global on the last step, which needs no mid-barrier).
    auto step = [&](bool first, bool last) {
        __syncthreads();
        float4 qm[4][2];
        float  e0[4], e3[4];
        if (act) {
            #pragma unroll
            for (int r = 0; r < 4; ++r) {
                e0[r] = buf[e0o[r]];
                e3[r] = buf[e3o[r]];
            }
            qm[0][0] = *(const float4*)(buf + rdm[0][0]);
            qm[0][1] = *(const float4*)(buf + rdm[0][1]);
            qm[3][0] = *(const float4*)(buf + rdm[3][0]);
            qm[3][1] = *(const float4*)(buf + rdm[3][1]);
            if (first) {
                qm[1][0] = *(const float4*)(buf + rdm[1][0]);
                qm[1][1] = *(const float4*)(buf + rdm[1][1]);
                qm[2][0] = *(const float4*)(buf + rdm[2][0]);
                qm[2][1] = *(const float4*)(buf + rdm[2][1]);
            } else {
                qm[1][0] = prev0[0]; qm[1][1] = prev1[0];
                qm[2][0] = prev0[1]; qm[2][1] = prev1[1];
            }
        }
        if (!last) __syncthreads();
        if (act) {
            __builtin_amdgcn_s_setprio(1);
            #pragma unroll
            for (int i = 0; i < 2; ++i) {
                float4 v0 = bu0[i];
                float4 v1 = bu1[i];
                acc_row(v0, e0[i],         qm[i][0],     qm[i][1].x,     k00, k01, k02);
                acc_row(v0, e0[i + 1],     qm[i + 1][0], qm[i + 1][1].x, k10, k11, k12);
                acc_row(v0, e0[i + 2],     qm[i + 2][0], qm[i + 2][1].x, k20, k21, k22);
                acc_row(v1, qm[i][0].w,     qm[i][1],     e3[i],         k00, k01, k02);
                acc_row(v1, qm[i + 1][0].w, qm[i + 1][1], e3[i + 1],     k10, k11, k12);
                acc_row(v1, qm[i + 2][0].w, qm[i + 2][1], e3[i + 2],     k20, k21, k22);
                clamp_mask(v0, pm0[i]);
                clamp_mask(v1, pm1[i]);
                if (!last) {
                    prev0[i] = v0;
                    prev1[i] = v1;
                    *(float4*)(buf + rdm[1 + i][0]) = v0;
                    *(float4*)(buf + rdm[1 + i][1]) = v1;
                } else {
                    int r = 2 * rp - 4 + i;              // tile-relative row
                    if ((unsigned)r < (unsigned)TH) {
                        float* dp = dst + base + (long)(bh0 + r) * HW + bw0 + 8 * j;
                        if (j >= 1) *(float4*)(dp - 4) = v0;   // cols 8j-4..8j-1
                        if (j <= 7) *(float4*)(dp)     = v1;   // cols 8j..8j+3
                    }
                }
            }
            __builtin_amdgcn_s_setprio(0);
        }
    };

    step(true,  false);
    step(false, false);
    step(false, false);
    step(false, false);
    step(false, true);   // direct global store; no mid-barrier, no LDS write
}

// ---------------------------------------------------------------------------
// Cross-scale 1x1-conv fusion: one thread per down-level pixel; U/X/D read
// exactly once, all three outputs written.
// ---------------------------------------------------------------------------
__global__ __launch_bounds__(256) void fuse_all(
    const float* __restrict__ X,   // 8 x 512^2
    const float* __restrict__ D,   // 8 x 256^2
    const float* __restrict__ U,   // 8 x 1024^2
    const float* __restrict__ cx,
    const float* __restrict__ cd,
    const float* __restrict__ cu,
    float* __restrict__ xo, float* __restrict__ dno, float* __restrict__ upo)
{
    const int total = NBATCH << 16;  // 8*256*256
    int idx = blockIdx.x * blockDim.x + threadIdx.x;
    if (idx >= total) return;
    int wd = idx & 255;
    int hd = (idx >> 8) & 255;
    int b  = idx >> 16;

    const float cx0 = cx[0], cx1 = cx[1], cx2 = cx[2];
    const float cd0 = cd[0], cd1 = cd[1], cd2 = cd[2];
    const float cu0 = cu[0], cu1 = cu[1], cu2 = cu[2];

    int ub = (b << 20) + ((hd << 2) << 10) + (wd << 2);
    float4 u0 = *(const float4*)&U[ub];
    float4 u1 = *(const float4*)&U[ub + 1024];
    float4 u2 = *(const float4*)&U[ub + 2048];
    float4 u3 = *(const float4*)&U[ub + 3072];
    int xb = (b << 18) + ((hd << 1) << 9) + (wd << 1);
    float2 x0 = *(const float2*)&X[xb];
    float2 x1 = *(const float2*)&X[xb + 512];
    float dv = D[idx];

    float p00 = 0.25f * (u0.x + u0.y + u1.x + u1.y);
    float p01 = 0.25f * (u0.z + u0.w + u1.z + u1.w);
    float p10 = 0.25f * (u2.x + u2.y + u3.x + u3.y);
    float p11 = 0.25f * (u2.z + u2.w + u3.z + u3.w);
    float pu4 = 0.25f * (p00 + p01 + p10 + p11);
    float px2 = 0.25f * (x0.x + x0.y + x1.x + x1.y);

    dno[idx] = cd0 * pu4 + cd1 * px2 + cd2 * dv;

    float2 xo0, xo1;
    xo0.x = cx0 * p00 + cx1 * x0.x + cx2 * dv;
    xo0.y = cx0 * p01 + cx1 * x0.y + cx2 * dv;
    xo1.x = cx0 * p10 + cx1 * x1.x + cx2 * dv;
    xo1.y = cx0 * p11 + cx1 * x1.y + cx2 * dv;
    *(float2*)&xo[xb]       = xo0;
    *(float2*)&xo[xb + 512] = xo1;

    float4 o0, o1, o2, o3;
    o0.x = cu0 * u0.x + cu1 * x0.x + cu2 * dv;
    o0.y = cu0 * u0.y + cu1 * x0.x + cu2 * dv;
    o0.z = cu0 * u0.z + cu1 * x0.y + cu2 * dv;
    o0.w = cu0 * u0.w + cu1 * x0.y + cu2 * dv;
    o1.x = cu0 * u1.x + cu1 * x0.x + cu2 * dv;
    o1.y = cu0 * u1.y + cu1 * x0.x + cu2 * dv;
    o1.z = cu0 * u1.z + cu1 * x0.y + cu2 * dv;
    o1.w = cu0 * u1.w + cu1 * x0.y + cu2 * dv;
    o2.x = cu0 * u2.x + cu1 * x1.x + cu2 * dv;
    o2.y = cu0 * u2.y + cu1 * x1.x + cu2 * dv;
    o2.z = cu0 * u2.z + cu1 * x1.y + cu2 * dv;
    o2.w = cu0 * u2.w + cu1 * x1.y + cu2 * dv;
    o3.x = cu0 * u3.x + cu1 * x1.x + cu2 * dv;
    o3.y = cu0 * u3.y + cu1 * x1.x + cu2 * dv;
    o3.z = cu0 * u3.z + cu1 * x1.y + cu2 * dv;
    o3.w = cu0 * u3.w + cu1 * x1.y + cu2 * dv;
    *(float4*)&upo[ub]        = o0;
    *(float4*)&upo[ub + 1024] = o1;
    *(float4*)&upo[ub + 2048] = o2;
    *(float4*)&upo[ub + 3072] = o3;
}

// ---------------------------------------------------------------------------
extern "C" void kernel_launch(void* const* d_in, const int* in_sizes, int n_in,
                              void* d_out, int out_size, void* d_ws, size_t ws_size,
                              hipStream_t stream)
{
    const float* x    = (const float*)d_in[0];
    const float* down = (const float*)d_in[1];
    const float* up   = (const float*)d_in[2];
    const float* BUx  = (const float*)d_in[3];
    const float* BUd  = (const float*)d_in[4];
    const float* BUu  = (const float*)d_in[5];
    const float* wAx  = (const float*)d_in[6];
    const float* bx   = (const float*)d_in[7];
    const float* wAd  = (const float*)d_in[8];
    const float* bd   = (const float*)d_in[9];
    const float* wAu  = (const float*)d_in[10];
    const float* bu   = (const float*)d_in[11];
    const float* c1x  = (const float*)d_in[12];
    const float* c1d  = (const float*)d_in[13];
    const float* c1u  = (const float*)d_in[14];

    float* out = (float*)d_out;
    float* ws  = (float*)d_ws;

    const int NX = NBATCH * 512 * 512;
    const int ND = NBATCH * 256 * 256;

    float* wsX = ws;
    float* wsD = ws + NX;
    float* wsU = ws + NX + ND;
    float* outX = out;
    float* outD = out + NX;
    float* outU = out + NX + ND;

    // one dispatch, all levels: 4096 up + 1024 x + 256 down tiles (64x32 each)
    conv5_all<<<5376, NTHR, 0, stream>>>(
        up,   BUu, wAu, bu,
        x,    BUx, wAx, bx,
        down, BUd, wAd, bd,
        wsU, wsX, wsD);

    fuse_all<<<(ND + 255) / 256, 256, 0, stream>>>(wsX, wsD, wsU, c1x, c1d, c1u,
                                                   outX, outD, outU);
}

// Round 9
// 369.786 us; speedup vs baseline: 1.2400x; 1.2400x over previous
//
#include <hip/hip_runtime.h>

#define NBATCH 8
#define TW 64          // tile width  (output)
#define TH 32          // tile height (output)
#define SROWS 42       // staged rows: image rows -5..36  (TH + 10)
#define SQUADS 20      // staged data quads/row: image cols -8..71 (80 floats)
#define STRDQ 80       // LDS row stride in floats (20 quads, rotation mod 20)
#define NPAIRS 20      // region row-pairs (region rows -4..35)
#define NSTRIP 180     // 20 row-pairs x 9 col-octs
#define NTHR 192
// LDS: ONE 42-row buffer @ 80 floats = 13440 B. In-place ping-pong: per step,
// all window reads complete (mid-barrier) before any in-place write ->
// 8-10 blocks/CU (24-30 waves) vs 6 blocks (18 waves) of the 2-buffer scheme.
// R8 lesson: launch_bounds(.,8) capped VGPR at 64, compiler picked 32 and
// spilled the across-barrier window to scratch (FETCH 83->620 MB, conv 4x
// slower). (.,6) gives ~85 VGPR headroom for the ~72 live registers.

// ---------------------------------------------------------------------------
// Swizzled LDS layout: logical quad q (0..19) of row R lives at physical quad
// (q + 3*(R>>1)) mod 20. Bank 4-group of an access = lane-varying (2j + 3rp)
// mod 8 balanced by the posmap strip assignment; the mod-20 wrap adds an
// approximate +4 perturbation (accepted, measured ~0.8e7 counter at R7).
// ---------------------------------------------------------------------------
__device__ __forceinline__ int lofs(int R, int q) {   // float offset of (row,quad)
    int rot = (3 * (R >> 1)) % 20;
    int p = q + rot;
    if (p >= 20) p -= 20;
    return R * STRDQ + (p << 2);
}

// accumulate one stencil row: window floats [L, m.x..m.w, R], weights ka,kb,kc
__device__ __forceinline__ void acc_row(float4& v, float L, float4 m, float R,
                                        float ka, float kb, float kc) {
    v.x += ka * L   + kb * m.x + kc * m.y;
    v.y += ka * m.x + kb * m.y + kc * m.z;
    v.z += ka * m.y + kb * m.z + kc * m.w;
    v.w += ka * m.z + kb * m.w + kc * R;
}

// clamp to [-1,1] then apply precomputed mask; all LDS inputs are finite by
// construction (buffer fully staged from finite input; rim cells keep staged
// halo data forever), so fmed3 NaN semantics never engage and out-of-image
// padding cells stay exactly 0.
__device__ __forceinline__ void clamp_mask(float4& v, float4 pm) {
    v.x = __builtin_amdgcn_fmed3f(v.x, -1.0f, 1.0f) * pm.x;
    v.y = __builtin_amdgcn_fmed3f(v.y, -1.0f, 1.0f) * pm.y;
    v.z = __builtin_amdgcn_fmed3f(v.z, -1.0f, 1.0f) * pm.z;
    v.w = __builtin_amdgcn_fmed3f(v.w, -1.0f, 1.0f) * pm.w;
}

// ---------------------------------------------------------------------------
// 5 fused conv3x3+bias+BU+clamp iterations; all 3 pyramid levels, one dispatch.
// One 64x32 output tile per 192-thread block. Single LDS buffer, in-place:
// per step {barrier; read window to regs; barrier; compute+write}. Thread t
// (<180) owns one 8x2-px strip. Window regs kept small: 4 middle float4s
// (rows 0,3) + 8 edge scalars (only .w/.x of edge quads are used) + 4 center
// float4s from this thread's own previous write (register mirror, steps 2-5).
// Step 5 stores result registers directly to global (interior-masked) with
// no mid-barrier or LDS write. Writes cover rows 1..40, quads 1..18; rim
// cells keep their staged halo values -- reads of them only feed eroded-ring
// cells, identical validity argument to the 2-buffer scheme (correctness
// verified by R8's passing absmax). Out-of-image cells re-masked to 0 every
// iter (true zero-pad semantics at image edges).
// ---------------------------------------------------------------------------
__global__ __launch_bounds__(NTHR, 6) void conv5_all(
    const float* __restrict__ srcU, const float* __restrict__ buU,
    const float* __restrict__ wtU, const float* __restrict__ bsU,
    const float* __restrict__ srcX, const float* __restrict__ buX,
    const float* __restrict__ wtX, const float* __restrict__ bsX,
    const float* __restrict__ srcD, const float* __restrict__ buD,
    const float* __restrict__ wtD, const float* __restrict__ bsD,
    float* __restrict__ dstU, float* __restrict__ dstX, float* __restrict__ dstD)
{
    __shared__ __align__(16) float buf[SROWS * STRDQ];

    const int tid = threadIdx.x;
    const int blk = blockIdx.x;

    const float* src; const float* BU; const float* wt; const float* bs;
    float* dst; int HW; int tx, ty, b;
    if (blk < 4096) {                 // up: 8 x (32 ty x 16 tx)
        src = srcU; BU = buU; wt = wtU; bs = bsU; dst = dstU; HW = 1024;
        b = blk >> 9; int rem = blk & 511; ty = rem >> 4; tx = rem & 15;
    } else if (blk < 5120) {          // x: 8 x (16 ty x 8 tx)
        int t = blk - 4096;
        src = srcX; BU = buX; wt = wtX; bs = bsX; dst = dstX; HW = 512;
        b = t >> 7; int rem = t & 127; ty = rem >> 3; tx = rem & 7;
    } else {                          // down: 8 x (8 ty x 4 tx)
        int t = blk - 5120;
        src = srcD; BU = buD; wt = wtD; bs = bsD; dst = dstD; HW = 256;
        b = t >> 5; int rem = t & 31; ty = rem >> 2; tx = rem & 3;
    }
    const int bh0 = ty * TH, bw0 = tx * TW;
    const long base = (long)b * HW * HW;

    // ---- stage: image rows -5..36, cols -8..71 -> buf (img col c -> data quad (c+8)/4)
    for (int s = tid; s < SROWS * SQUADS; s += NTHR) {
        int r = s / SQUADS, cq = s - r * SQUADS;
        int gh = bh0 + r - 5;
        int gw = bw0 + (cq << 2) - 8;
        float4 v = {0.0f, 0.0f, 0.0f, 0.0f};
        if ((unsigned)gh < (unsigned)HW) {
            const float* gp = src + base + (long)gh * HW + gw;
            if (gw >= 0 && gw + 3 < HW) {
                v = *(const float4*)gp;
            } else {
                if ((unsigned)(gw + 0) < (unsigned)HW) v.x = gp[0];
                if ((unsigned)(gw + 1) < (unsigned)HW) v.y = gp[1];
                if ((unsigned)(gw + 2) < (unsigned)HW) v.z = gp[2];
                if ((unsigned)(gw + 3) < (unsigned)HW) v.w = gp[3];
            }
        }
        *(float4*)&buf[lofs(r, cq)] = v;
    }

    const float k00 = wt[0], k01 = wt[1], k02 = wt[2];
    const float k10 = wt[3], k11 = wt[4], k12 = wt[5];
    const float k20 = wt[6], k21 = wt[7], k22 = wt[8];
    const float bias = bs[0];

    // ---- strip assignment: thread t -> (t>>3)-th strip of bank-group
    // posmap[t&7] (balances the un-wrapped (2j+3rp) mod 8 component).
    // Groups {0,1,3,6} have 23 strips, {2,4,5,7} have 22. Within row-pair rp,
    // strips of group g exist iff rp parity == g parity, at j = j0 + 4*m
    // (j0 = ((g-3rp)&7)>>1; m = 0..2 if j0==0 else 0..1).
    const bool act = (tid < NSTRIP);
    int rp = 0, j = 0;
    {
        int g = (0x75426310u >> ((tid & 7) << 2)) & 0xF;  // posmap {0,1,3,6,2,4,5,7}
        int need = tid >> 3;
        for (int r_ = (g & 1); r_ < NPAIRS; r_ += 2) {
            int j0 = ((g - 3 * r_) & 7) >> 1;             // 0..3
            int c = (j0 == 0) ? 3 : 2;
            if (need < c) { rp = r_; j = j0 + 4 * need; break; }
            need -= c;
        }
    }

    // precomputed swizzled LDS offsets (constant across all 5 steps):
    // middle quads (b128) at logical quads 2j+1, 2j+2; edge floats (b32)
    // L = quad 2j elem 3, R = quad 2j+3 elem 0.
    int rdm[4][2];
    int e0o[4], e3o[4];
    #pragma unroll
    for (int r = 0; r < 4; ++r) {
        rdm[r][0] = lofs(2 * rp + r, 2 * j + 1);
        rdm[r][1] = lofs(2 * rp + r, 2 * j + 2);
        e0o[r]    = lofs(2 * rp + r, 2 * j) + 3;
        e3o[r]    = lofs(2 * rp + r, 2 * j + 3);
    }
    // write offsets == rdm[1..2][0..1] (rows 2rp+1..2, quads 2j+1..2)

    // ---- premultiplied masks pm = hf(row-in-image) * wf(col-in-image)
    float4 pm0[2], pm1[2];
    float hf[2];
    #pragma unroll
    for (int i = 0; i < 2; ++i) {
        int gh = bh0 + 2 * rp - 4 + i;
        hf[i] = (act && (unsigned)gh < (unsigned)HW) ? 1.0f : 0.0f;
        float* p0 = (float*)&pm0[i]; float* p1 = (float*)&pm1[i];
        #pragma unroll
        for (int k = 0; k < 4; ++k) {
            p0[k] = hf[i] * (((unsigned)(bw0 + 8 * j - 4 + k) < (unsigned)HW) ? 1.0f : 0.0f);
            p1[k] = hf[i] * (((unsigned)(bw0 + 8 * j + k)     < (unsigned)HW) ? 1.0f : 0.0f);
        }
    }
    float4 bu0[2], bu1[2];            // (BU + bias), pre-masked 0 outside image
    #pragma unroll
    for (int i = 0; i < 2; ++i) {
        int gh = bh0 + 2 * rp - 4 + i;
        bool hok = (hf[i] != 0.0f);
        int gw0 = bw0 + 8 * j - 4;    // 4-aligned
        const float* bp = BU + base + (long)gh * HW + gw0;
        if (hok && gw0 >= 0 && gw0 + 7 < HW) {
            // interior fast path: two aligned float4 loads
            float4 a = *(const float4*)bp;
            float4 c = *(const float4*)(bp + 4);
            bu0[i] = {a.x + bias, a.y + bias, a.z + bias, a.w + bias};
            bu1[i] = {c.x + bias, c.y + bias, c.z + bias, c.w + bias};
        } else {
            float* b0 = (float*)&bu0[i]; float* b1 = (float*)&bu1[i];
            #pragma unroll
            for (int k = 0; k < 4; ++k) {
                int w0 = gw0 + k;
                int w1 = gw0 + 4 + k;
                b0[k] = (hok && (unsigned)w0 < (unsigned)HW) ? (bp[k] + bias)     : 0.0f;
                b1[k] = (hok && (unsigned)w1 < (unsigned)HW) ? (bp[k + 4] + bias) : 0.0f;
            }
        }
    }

    // center quads this thread wrote last step (registers mirror LDS exactly)
    float4 prev0[2], prev1[2];

    // ---- one in-place conv step:
    //   barrier (prev writes / staging visible) -> read window to regs ->
    //   barrier (all reads done) -> compute -> write in place (or store
    //   directly to global on the last step, which needs no mid-barrier).
    auto step = [&](bool first, bool last) {
        __syncthreads();
        float4 qm[4][2];
        float  e0[4], e3[4];
        if (act) {
            #pragma unroll
            for (int r = 0; r < 4; ++r) {
                e0[r] = buf[e0o[r]];
                e3[r] = buf[e3o[r]];
            }
            qm[0][0] = *(const float4*)(buf + rdm[0][0]);
            qm[0][1] = *(const float4*)(buf + rdm[0][1]);
            qm[3][0] = *(const float4*)(buf + rdm[3][0]);
            qm[3][1] = *(const float4*)(buf + rdm[3][1]);
            if (first) {
                qm[1][0] = *(const float4*)(buf + rdm[1][0]);
                qm[1][1] = *(const float4*)(buf + rdm[1][1]);
                qm[2][0] = *(const float4*)(buf + rdm[2][0]);
                qm[2][1] = *(const float4*)(buf + rdm[2][1]);
            } else {
                qm[1][0] = prev0[0]; qm[1][1] = prev1[0];
                qm[2][0] = prev0[1]; qm[2][1] = prev1[1];
            }
        }
        if (!last) __syncthreads();
        if (act) {
            __builtin_amdgcn_s_setprio(1);
            #pragma unroll
            for (int i = 0; i < 2; ++i) {
                float4 v0 = bu0[i];
                float4 v1 = bu1[i];
                acc_row(v0, e0[i],         qm[i][0],     qm[i][1].x,     k00, k01, k02);
                acc_row(v0, e0[i + 1],     qm[i + 1][0], qm[i + 1][1].x, k10, k11, k12);
                acc_row(v0, e0[i + 2],     qm[i + 2][0], qm[i + 2][1].x, k20, k21, k22);
                acc_row(v1, qm[i][0].w,     qm[i][1],     e3[i],         k00, k01, k02);
                acc_row(v1, qm[i + 1][0].w, qm[i + 1][1], e3[i + 1],     k10, k11, k12);
                acc_row(v1, qm[i + 2][0].w, qm[i + 2][1], e3[i + 2],     k20, k21, k22);
                clamp_mask(v0, pm0[i]);
                clamp_mask(v1, pm1[i]);
                if (!last) {
                    prev0[i] = v0;
                    prev1[i] = v1;
                    *(float4*)(buf + rdm[1 + i][0]) = v0;
                    *(float4*)(buf + rdm[1 + i][1]) = v1;
                } else {
                    int r = 2 * rp - 4 + i;              // tile-relative row
                    if ((unsigned)r < (unsigned)TH) {
                        float* dp = dst + base + (long)(bh0 + r) * HW + bw0 + 8 * j;
                        if (j >= 1) *(float4*)(dp - 4) = v0;   // cols 8j-4..8j-1
                        if (j <= 7) *(float4*)(dp)     = v1;   // cols 8j..8j+3
                    }
                }
            }
            __builtin_amdgcn_s_setprio(0);
        }
    };

    step(true,  false);
    step(false, false);
    step(false, false);
    step(false, false);
    step(false, true);   // direct global store; no mid-barrier, no LDS write
}

// ---------------------------------------------------------------------------
// Cross-scale 1x1-conv fusion: one thread per down-level pixel; U/X/D read
// exactly once, all three outputs written.
// ---------------------------------------------------------------------------
__global__ __launch_bounds__(256) void fuse_all(
    const float* __restrict__ X,   // 8 x 512^2
    const float* __restrict__ D,   // 8 x 256^2
    const float* __restrict__ U,   // 8 x 1024^2
    const float* __restrict__ cx,
    const float* __restrict__ cd,
    const float* __restrict__ cu,
    float* __restrict__ xo, float* __restrict__ dno, float* __restrict__ upo)
{
    const int total = NBATCH << 16;  // 8*256*256
    int idx = blockIdx.x * blockDim.x + threadIdx.x;
    if (idx >= total) return;
    int wd = idx & 255;
    int hd = (idx >> 8) & 255;
    int b  = idx >> 16;

    const float cx0 = cx[0], cx1 = cx[1], cx2 = cx[2];
    const float cd0 = cd[0], cd1 = cd[1], cd2 = cd[2];
    const float cu0 = cu[0], cu1 = cu[1], cu2 = cu[2];

    int ub = (b << 20) + ((hd << 2) << 10) + (wd << 2);
    float4 u0 = *(const float4*)&U[ub];
    float4 u1 = *(const float4*)&U[ub + 1024];
    float4 u2 = *(const float4*)&U[ub + 2048];
    float4 u3 = *(const float4*)&U[ub + 3072];
    int xb = (b << 18) + ((hd << 1) << 9) + (wd << 1);
    float2 x0 = *(const float2*)&X[xb];
    float2 x1 = *(const float2*)&X[xb + 512];
    float dv = D[idx];

    float p00 = 0.25f * (u0.x + u0.y + u1.x + u1.y);
    float p01 = 0.25f * (u0.z + u0.w + u1.z + u1.w);
    float p10 = 0.25f * (u2.x + u2.y + u3.x + u3.y);
    float p11 = 0.25f * (u2.z + u2.w + u3.z + u3.w);
    float pu4 = 0.25f * (p00 + p01 + p10 + p11);
    float px2 = 0.25f * (x0.x + x0.y + x1.x + x1.y);

    dno[idx] = cd0 * pu4 + cd1 * px2 + cd2 * dv;

    float2 xo0, xo1;
    xo0.x = cx0 * p00 + cx1 * x0.x + cx2 * dv;
    xo0.y = cx0 * p01 + cx1 * x0.y + cx2 * dv;
    xo1.x = cx0 * p10 + cx1 * x1.x + cx2 * dv;
    xo1.y = cx0 * p11 + cx1 * x1.y + cx2 * dv;
    *(float2*)&xo[xb]       = xo0;
    *(float2*)&xo[xb + 512] = xo1;

    float4 o0, o1, o2, o3;
    o0.x = cu0 * u0.x + cu1 * x0.x + cu2 * dv;
    o0.y = cu0 * u0.y + cu1 * x0.x + cu2 * dv;
    o0.z = cu0 * u0.z + cu1 * x0.y + cu2 * dv;
    o0.w = cu0 * u0.w + cu1 * x0.y + cu2 * dv;
    o1.x = cu0 * u1.x + cu1 * x0.x + cu2 * dv;
    o1.y = cu0 * u1.y + cu1 * x0.x + cu2 * dv;
    o1.z = cu0 * u1.z + cu1 * x0.y + cu2 * dv;
    o1.w = cu0 * u1.w + cu1 * x0.y + cu2 * dv;
    o2.x = cu0 * u2.x + cu1 * x1.x + cu2 * dv;
    o2.y = cu0 * u2.y + cu1 * x1.x + cu2 * dv;
    o2.z = cu0 * u2.z + cu1 * x1.y + cu2 * dv;
    o2.w = cu0 * u2.w + cu1 * x1.y + cu2 * dv;
    o3.x = cu0 * u3.x + cu1 * x1.x + cu2 * dv;
    o3.y = cu0 * u3.y + cu1 * x1.x + cu2 * dv;
    o3.z = cu0 * u3.z + cu1 * x1.y + cu2 * dv;
    o3.w = cu0 * u3.w + cu1 * x1.y + cu2 * dv;
    *(float4*)&upo[ub]        = o0;
    *(float4*)&upo[ub + 1024] = o1;
    *(float4*)&upo[ub + 2048] = o2;
    *(float4*)&upo[ub + 3072] = o3;
}

// ---------------------------------------------------------------------------
extern "C" void kernel_launch(void* const* d_in, const int* in_sizes, int n_in,
                              void* d_out, int out_size, void* d_ws, size_t ws_size,
                              hipStream_t stream)
{
    const float* x    = (const float*)d_in[0];
    const float* down = (const float*)d_in[1];
    const float* up   = (const float*)d_in[2];
    const float* BUx  = (const float*)d_in[3];
    const float* BUd  = (const float*)d_in[4];
    const float* BUu  = (const float*)d_in[5];
    const float* wAx  = (const float*)d_in[6];
    const float* bx   = (const float*)d_in[7];
    const float* wAd  = (const float*)d_in[8];
    const float* bd   = (const float*)d_in[9];
    const float* wAu  = (const float*)d_in[10];
    const float* bu   = (const float*)d_in[11];
    const float* c1x  = (const float*)d_in[12];
    const float* c1d  = (const float*)d_in[13];
    const float* c1u  = (const float*)d_in[14];

    float* out = (float*)d_out;
    float* ws  = (float*)d_ws;

    const int NX = NBATCH * 512 * 512;
    const int ND = NBATCH * 256 * 256;

    float* wsX = ws;
    float* wsD = ws + NX;
    float* wsU = ws + NX + ND;
    float* outX = out;
    float* outD = out + NX;
    float* outU = out + NX + ND;

    // one dispatch, all levels: 4096 up + 1024 x + 256 down tiles (64x32 each)
    conv5_all<<<5376, NTHR, 0, stream>>>(
        up,   BUu, wAu, bu,
        x,    BUx, wAx, bx,
        down, BUd, wAd, bd,
        wsU, wsX, wsD);

    fuse_all<<<(ND + 255) / 256, 256, 0, stream>>>(wsX, wsD, wsU, c1x, c1d, c1u,
                                                   outX, outD, outU);
}

// Round 10
// 206.982 us; speedup vs baseline: 2.2153x; 1.7866x over previous
//
#include <hip/hip_runtime.h>

#define NBATCH 8
#define TW 64          // tile width  (output)
#define TH 32          // tile height (output)
#define SROWS 42       // staged rows: image rows -5..36  (TH + 10)
#define SQUADS 20      // staged data quads/row: image cols -8..71 (80 floats)
#define STRDQ 80       // LDS row stride in floats (20 quads, rotation mod 20)
#define NPAIRS 20      // region row-pairs (region rows -4..35)
#define NSTRIP 180     // 20 row-pairs x 9 col-octs
#define NTHR 192
// LDS: two 42-row buffers @ 80 floats = 26880 B -> 6 blocks/CU (18 waves).
// R8/R9 lesson: the in-place single-buffer scheme needs ~72 live VGPRs across
// a mid-barrier; gfx950's occupancy tiers (8 waves/SIMD at <=64 VGPR, 4 at
// <=128) make that either spill (capped) or LOSE waves (uncapped 16/CU tier).
// This 2-buffer / 48-VGPR / 18-wave configuration is the measured optimum.

// ---------------------------------------------------------------------------
// Swizzled LDS layout: logical quad q (0..19) of row R lives at physical quad
// (q + 3*(R>>1)) mod 20. Bank 4-group of an access = lane-varying (2j + 3rp)
// mod 8 balanced by the posmap strip assignment; the mod-20 wrap adds an
// approximate +4 perturbation (accepted, measured ~0.8e7 counter at R7).
// ---------------------------------------------------------------------------
__device__ __forceinline__ int lofs(int R, int q) {   // float offset of (row,quad)
    int rot = (3 * (R >> 1)) % 20;
    int p = q + rot;
    if (p >= 20) p -= 20;
    return R * STRDQ + (p << 2);
}

// accumulate one stencil row: window floats [L, m.x..m.w, R], weights ka,kb,kc
__device__ __forceinline__ void acc_row(float4& v, float L, float4 m, float R,
                                        float ka, float kb, float kc) {
    v.x += ka * L   + kb * m.x + kc * m.y;
    v.y += ka * m.x + kb * m.y + kc * m.z;
    v.z += ka * m.y + kb * m.z + kc * m.w;
    v.w += ka * m.z + kb * m.w + kc * R;
}

// clamp to [-1,1] then apply precomputed mask; all LDS inputs are finite by
// construction (A fully staged, B written-or-zeroed), so fmed3 NaN semantics
// never engage and out-of-image padding cells stay exactly 0.
__device__ __forceinline__ void clamp_mask(float4& v, float4 pm) {
    v.x = __builtin_amdgcn_fmed3f(v.x, -1.0f, 1.0f) * pm.x;
    v.y = __builtin_amdgcn_fmed3f(v.y, -1.0f, 1.0f) * pm.y;
    v.z = __builtin_amdgcn_fmed3f(v.z, -1.0f, 1.0f) * pm.z;
    v.w = __builtin_amdgcn_fmed3f(v.w, -1.0f, 1.0f) * pm.w;
}

// ---------------------------------------------------------------------------
// 5 fused conv3x3+bias+BU+clamp iterations; all 3 pyramid levels, one dispatch.
// One 64x32 output tile per 192-thread block. LDS ping-pong 26.9KB (6 blk/CU).
// Thread t (<180) owns one 8x2-px strip. Step 1: 16 ds_read_b128; steps 2-5:
// 12 (4 center quads come from this thread's own previous writes, kept in
// registers, bit-identical). Steps 1-4: 4 ds_write_b128. Step 5 stores its
// result registers DIRECTLY to global (interior-masked; quads align with the
// interior boundary so masks are per-quad bools) -- no epilogue phase.
// 6 barriers total. setprio(1) wraps each step's compute. Computed region
// rows -4..35, cols -4..67; validity erodes 1 ring/iter, leaving the exact
// 64x32 interior after 5 iters. Out-of-image cells re-masked to 0 every iter.
// ---------------------------------------------------------------------------
__global__ __launch_bounds__(NTHR, 4) void conv5_all(
    const float* __restrict__ srcU, const float* __restrict__ buU,
    const float* __restrict__ wtU, const float* __restrict__ bsU,
    const float* __restrict__ srcX, const float* __restrict__ buX,
    const float* __restrict__ wtX, const float* __restrict__ bsX,
    const float* __restrict__ srcD, const float* __restrict__ buD,
    const float* __restrict__ wtD, const float* __restrict__ bsD,
    float* __restrict__ dstU, float* __restrict__ dstX, float* __restrict__ dstD)
{
    __shared__ __align__(16) float bufA[SROWS * STRDQ];
    __shared__ __align__(16) float bufB[SROWS * STRDQ];

    const int tid = threadIdx.x;
    const int blk = blockIdx.x;

    const float* src; const float* BU; const float* wt; const float* bs;
    float* dst; int HW; int tx, ty, b;
    if (blk < 4096) {                 // up: 8 x (32 ty x 16 tx)
        src = srcU; BU = buU; wt = wtU; bs = bsU; dst = dstU; HW = 1024;
        b = blk >> 9; int rem = blk & 511; ty = rem >> 4; tx = rem & 15;
    } else if (blk < 5120) {          // x: 8 x (16 ty x 8 tx)
        int t = blk - 4096;
        src = srcX; BU = buX; wt = wtX; bs = bsX; dst = dstX; HW = 512;
        b = t >> 7; int rem = t & 127; ty = rem >> 3; tx = rem & 7;
    } else {                          // down: 8 x (8 ty x 4 tx)
        int t = blk - 5120;
        src = srcD; BU = buD; wt = wtD; bs = bsD; dst = dstD; HW = 256;
        b = t >> 5; int rem = t & 31; ty = rem >> 2; tx = rem & 3;
    }
    const int bh0 = ty * TH, bw0 = tx * TW;
    const long base = (long)b * HW * HW;

    // ---- stage: image rows -5..36, cols -8..71 -> bufA (img col c -> data quad (c+8)/4)
    for (int s = tid; s < SROWS * SQUADS; s += NTHR) {
        int r = s / SQUADS, cq = s - r * SQUADS;
        int gh = bh0 + r - 5;
        int gw = bw0 + (cq << 2) - 8;
        float4 v = {0.0f, 0.0f, 0.0f, 0.0f};
        if ((unsigned)gh < (unsigned)HW) {
            const float* gp = src + base + (long)gh * HW + gw;
            if (gw >= 0 && gw + 3 < HW) {
                v = *(const float4*)gp;
            } else {
                if ((unsigned)(gw + 0) < (unsigned)HW) v.x = gp[0];
                if ((unsigned)(gw + 1) < (unsigned)HW) v.y = gp[1];
                if ((unsigned)(gw + 2) < (unsigned)HW) v.z = gp[2];
                if ((unsigned)(gw + 3) < (unsigned)HW) v.w = gp[3];
            }
        }
        *(float4*)&bufA[lofs(r, cq)] = v;
    }
    // ---- zero bufB's never-written cells (rows {0,41} all quads; quads {0,19}
    // of rows 1..40): 120 quads, one wave-op round -> every LDS read finite.
    for (int s = tid; s < 120; s += NTHR) {
        int r, q;
        if (s < 40)      { r = (s < 20) ? 0 : 41; q = s % 20; }
        else             { int s2 = s - 40; r = 1 + (s2 >> 1); q = (s2 & 1) ? 19 : 0; }
        float4 z = {0.0f, 0.0f, 0.0f, 0.0f};
        *(float4*)&bufB[lofs(r, q)] = z;
    }

    const float k00 = wt[0], k01 = wt[1], k02 = wt[2];
    const float k10 = wt[3], k11 = wt[4], k12 = wt[5];
    const float k20 = wt[6], k21 = wt[7], k22 = wt[8];
    const float bias = bs[0];

    // ---- strip assignment: thread t -> (t>>3)-th strip of bank-group
    // posmap[t&7] (balances the un-wrapped (2j+3rp) mod 8 component).
    // Groups {0,1,3,6} have 23 strips, {2,4,5,7} have 22. Within row-pair rp,
    // strips of group g exist iff rp parity == g parity, at j = j0 + 4*m
    // (j0 = ((g-3rp)&7)>>1; m = 0..2 if j0==0 else 0..1).
    const bool act = (tid < NSTRIP);
    int rp = 0, j = 0;
    {
        int g = (0x75426310u >> ((tid & 7) << 2)) & 0xF;  // posmap {0,1,3,6,2,4,5,7}
        int need = tid >> 3;
        for (int r_ = (g & 1); r_ < NPAIRS; r_ += 2) {
            int j0 = ((g - 3 * r_) & 7) >> 1;             // 0..3
            int c = (j0 == 0) ? 3 : 2;
            if (need < c) { rp = r_; j = j0 + 4 * need; break; }
            need -= c;
        }
    }

    // precomputed swizzled LDS offsets (constant across all 5 steps)
    int rdo[4][4];
    #pragma unroll
    for (int r = 0; r < 4; ++r)
        #pragma unroll
        for (int c = 0; c < 4; ++c)
            rdo[r][c] = lofs(2 * rp + r, 2 * j + c);
    int wro[2][2];
    #pragma unroll
    for (int i = 0; i < 2; ++i) {
        wro[i][0] = lofs(2 * rp + 1 + i, 2 * j + 1);
        wro[i][1] = lofs(2 * rp + 1 + i, 2 * j + 2);
    }

    // ---- premultiplied masks pm = hf(row-in-image) * wf(col-in-image)
    float4 pm0[2], pm1[2];
    float hf[2];
    #pragma unroll
    for (int i = 0; i < 2; ++i) {
        int gh = bh0 + 2 * rp - 4 + i;
        hf[i] = (act && (unsigned)gh < (unsigned)HW) ? 1.0f : 0.0f;
        float* p0 = (float*)&pm0[i]; float* p1 = (float*)&pm1[i];
        #pragma unroll
        for (int k = 0; k < 4; ++k) {
            p0[k] = hf[i] * (((unsigned)(bw0 + 8 * j - 4 + k) < (unsigned)HW) ? 1.0f : 0.0f);
            p1[k] = hf[i] * (((unsigned)(bw0 + 8 * j + k)     < (unsigned)HW) ? 1.0f : 0.0f);
        }
    }
    float4 bu0[2], bu1[2];            // (BU + bias), pre-masked 0 outside image
    #pragma unroll
    for (int i = 0; i < 2; ++i) {
        int gh = bh0 + 2 * rp - 4 + i;
        bool hok = (hf[i] != 0.0f);
        int gw0 = bw0 + 8 * j - 4;    // 4-aligned
        const float* bp = BU + base + (long)gh * HW + gw0;
        if (hok && gw0 >= 0 && gw0 + 7 < HW) {
            // interior fast path: two aligned float4 loads
            float4 a = *(const float4*)bp;
            float4 c = *(const float4*)(bp + 4);
            bu0[i] = {a.x + bias, a.y + bias, a.z + bias, a.w + bias};
            bu1[i] = {c.x + bias, c.y + bias, c.z + bias, c.w + bias};
        } else {
            float* b0 = (float*)&bu0[i]; float* b1 = (float*)&bu1[i];
            #pragma unroll
            for (int k = 0; k < 4; ++k) {
                int w0 = gw0 + k;
                int w1 = gw0 + 4 + k;
                b0[k] = (hok && (unsigned)w0 < (unsigned)HW) ? (bp[k] + bias)     : 0.0f;
                b1[k] = (hok && (unsigned)w1 < (unsigned)HW) ? (bp[k + 4] + bias) : 0.0f;
            }
        }
    }

    // center quads this thread wrote last step (registers mirror LDS exactly)
    float4 prev0[2], prev1[2];

    // ---- one conv step: read window from cs; write clamped result to ns
    // (steps 1-4) or store directly to global (step 5).
    auto step = [&](const float* __restrict__ cs, float* __restrict__ ns,
                    bool first, bool last) {
        __syncthreads();
        if (act) {
            float4 q[4][4];
            #pragma unroll
            for (int r = 0; r < 4; ++r) {
                q[r][0] = *(const float4*)(cs + rdo[r][0]);
                q[r][3] = *(const float4*)(cs + rdo[r][3]);
            }
            q[0][1] = *(const float4*)(cs + rdo[0][1]);
            q[0][2] = *(const float4*)(cs + rdo[0][2]);
            q[3][1] = *(const float4*)(cs + rdo[3][1]);
            q[3][2] = *(const float4*)(cs + rdo[3][2]);
            if (first) {
                q[1][1] = *(const float4*)(cs + rdo[1][1]);
                q[1][2] = *(const float4*)(cs + rdo[1][2]);
                q[2][1] = *(const float4*)(cs + rdo[2][1]);
                q[2][2] = *(const float4*)(cs + rdo[2][2]);
            } else {
                q[1][1] = prev0[0];
                q[1][2] = prev1[0];
                q[2][1] = prev0[1];
                q[2][2] = prev1[1];
            }
            __builtin_amdgcn_s_setprio(1);
            #pragma unroll
            for (int i = 0; i < 2; ++i) {
                float4 v0 = bu0[i];
                float4 v1 = bu1[i];
                acc_row(v0, q[i][0].w,     q[i][1],     q[i][2].x,     k00, k01, k02);
                acc_row(v0, q[i + 1][0].w, q[i + 1][1], q[i + 1][2].x, k10, k11, k12);
                acc_row(v0, q[i + 2][0].w, q[i + 2][1], q[i + 2][2].x, k20, k21, k22);
                acc_row(v1, q[i][1].w,     q[i][2],     q[i][3].x,     k00, k01, k02);
                acc_row(v1, q[i + 1][1].w, q[i + 1][2], q[i + 1][3].x, k10, k11, k12);
                acc_row(v1, q[i + 2][1].w, q[i + 2][2], q[i + 2][3].x, k20, k21, k22);
                clamp_mask(v0, pm0[i]);
                clamp_mask(v1, pm1[i]);
                if (!last) {
                    prev0[i] = v0;
                    prev1[i] = v1;
                    *(float4*)(ns + wro[i][0]) = v0;
                    *(float4*)(ns + wro[i][1]) = v1;
                } else {
                    int r = 2 * rp - 4 + i;              // tile-relative row
                    if ((unsigned)r < (unsigned)TH) {
                        float* dp = dst + base + (long)(bh0 + r) * HW + bw0 + 8 * j;
                        if (j >= 1) *(float4*)(dp - 4) = v0;   // cols 8j-4..8j-1
                        if (j <= 7) *(float4*)(dp)     = v1;   // cols 8j..8j+3
                    }
                }
            }
            __builtin_amdgcn_s_setprio(0);
        }
    };

    step(bufA, bufB, true,  false);
    step(bufB, bufA, false, false);
    step(bufA, bufB, false, false);
    step(bufB, bufA, false, false);
    step(bufA, bufB, false, true);   // direct global store; no epilogue barrier
}

// ---------------------------------------------------------------------------
// Cross-scale 1x1-conv fusion, v2: TWO vertically-adjacent down-pixels per
// thread (262144 threads, 1024 blocks). Halves wave count and doubles
// per-thread ILP (two independent load chains in flight) while keeping every
// instruction perfectly lane-coalesced (column mapping wd = idx&255
// unchanged). U/X/D read exactly once, all three outputs written once.
// ---------------------------------------------------------------------------
__global__ __launch_bounds__(256) void fuse_all(
    const float* __restrict__ X,   // 8 x 512^2
    const float* __restrict__ D,   // 8 x 256^2
    const float* __restrict__ U,   // 8 x 1024^2
    const float* __restrict__ cx,
    const float* __restrict__ cd,
    const float* __restrict__ cu,
    float* __restrict__ xo, float* __restrict__ dno, float* __restrict__ upo)
{
    int idx = blockIdx.x * blockDim.x + threadIdx.x;   // grid exactly covers
    int wd = idx & 255;
    int hp = (idx >> 8) & 127;     // down-row pair
    int b  = idx >> 15;

    const float cx0 = cx[0], cx1 = cx[1], cx2 = cx[2];
    const float cd0 = cd[0], cd1 = cd[1], cd2 = cd[2];
    const float cu0 = cu[0], cu1 = cu[1], cu2 = cu[2];

    #pragma unroll
    for (int i = 0; i < 2; ++i) {
        int hd = hp * 2 + i;
        int didx = (b << 16) + (hd << 8) + wd;

        int ub = (b << 20) + (hd << 12) + (wd << 2);
        float4 u0 = *(const float4*)&U[ub];
        float4 u1 = *(const float4*)&U[ub + 1024];
        float4 u2 = *(const float4*)&U[ub + 2048];
        float4 u3 = *(const float4*)&U[ub + 3072];
        int xb = (b << 18) + (hd << 10) + (wd << 1);
        float2 x0 = *(const float2*)&X[xb];
        float2 x1 = *(const float2*)&X[xb + 512];
        float dv = D[didx];

        float p00 = 0.25f * (u0.x + u0.y + u1.x + u1.y);
        float p01 = 0.25f * (u0.z + u0.w + u1.z + u1.w);
        float p10 = 0.25f * (u2.x + u2.y + u3.x + u3.y);
        float p11 = 0.25f * (u2.z + u2.w + u3.z + u3.w);
        float pu4 = 0.25f * (p00 + p01 + p10 + p11);
        float px2 = 0.25f * (x0.x + x0.y + x1.x + x1.y);

        dno[didx] = cd0 * pu4 + cd1 * px2 + cd2 * dv;

        float2 xo0, xo1;
        xo0.x = cx0 * p00 + cx1 * x0.x + cx2 * dv;
        xo0.y = cx0 * p01 + cx1 * x0.y + cx2 * dv;
        xo1.x = cx0 * p10 + cx1 * x1.x + cx2 * dv;
        xo1.y = cx0 * p11 + cx1 * x1.y + cx2 * dv;
        *(float2*)&xo[xb]       = xo0;
        *(float2*)&xo[xb + 512] = xo1;

        float4 o0, o1, o2, o3;
        o0.x = cu0 * u0.x + cu1 * x0.x + cu2 * dv;
        o0.y = cu0 * u0.y + cu1 * x0.x + cu2 * dv;
        o0.z = cu0 * u0.z + cu1 * x0.y + cu2 * dv;
        o0.w = cu0 * u0.w + cu1 * x0.y + cu2 * dv;
        o1.x = cu0 * u1.x + cu1 * x0.x + cu2 * dv;
        o1.y = cu0 * u1.y + cu1 * x0.x + cu2 * dv;
        o1.z = cu0 * u1.z + cu1 * x0.y + cu2 * dv;
        o1.w = cu0 * u1.w + cu1 * x0.y + cu2 * dv;
        o2.x = cu0 * u2.x + cu1 * x1.x + cu2 * dv;
        o2.y = cu0 * u2.y + cu1 * x1.x + cu2 * dv;
        o2.z = cu0 * u2.z + cu1 * x1.y + cu2 * dv;
        o2.w = cu0 * u2.w + cu1 * x1.y + cu2 * dv;
        o3.x = cu0 * u3.x + cu1 * x1.x + cu2 * dv;
        o3.y = cu0 * u3.y + cu1 * x1.x + cu2 * dv;
        o3.z = cu0 * u3.z + cu1 * x1.y + cu2 * dv;
        o3.w = cu0 * u3.w + cu1 * x1.y + cu2 * dv;
        *(float4*)&upo[ub]        = o0;
        *(float4*)&upo[ub + 1024] = o1;
        *(float4*)&upo[ub + 2048] = o2;
        *(float4*)&upo[ub + 3072] = o3;
    }
}

// ---------------------------------------------------------------------------
extern "C" void kernel_launch(void* const* d_in, const int* in_sizes, int n_in,
                              void* d_out, int out_size, void* d_ws, size_t ws_size,
                              hipStream_t stream)
{
    const float* x    = (const float*)d_in[0];
    const float* down = (const float*)d_in[1];
    const float* up   = (const float*)d_in[2];
    const float* BUx  = (const float*)d_in[3];
    const float* BUd  = (const float*)d_in[4];
    const float* BUu  = (const float*)d_in[5];
    const float* wAx  = (const float*)d_in[6];
    const float* bx   = (const float*)d_in[7];
    const float* wAd  = (const float*)d_in[8];
    const float* bd   = (const float*)d_in[9];
    const float* wAu  = (const float*)d_in[10];
    const float* bu   = (const float*)d_in[11];
    const float* c1x  = (const float*)d_in[12];
    const float* c1d  = (const float*)d_in[13];
    const float* c1u  = (const float*)d_in[14];

    float* out = (float*)d_out;
    float* ws  = (float*)d_ws;

    const int NX = NBATCH * 512 * 512;
    const int ND = NBATCH * 256 * 256;

    float* wsX = ws;
    float* wsD = ws + NX;
    float* wsU = ws + NX + ND;
    float* outX = out;
    float* outD = out + NX;
    float* outU = out + NX + ND;

    // one dispatch, all levels: 4096 up + 1024 x + 256 down tiles (64x32 each)
    conv5_all<<<5376, NTHR, 0, stream>>>(
        up,   BUu, wAu, bu,
        x,    BUx, wAx, bx,
        down, BUd, wAd, bd,
        wsU, wsX, wsD);

    // 262144 threads (2 down-pixels each), exact grid
    fuse_all<<<1024, 256, 0, stream>>>(wsX, wsD, wsU, c1x, c1d, c1u,
                                       outX, outD, outU);
}